// Round 12
// baseline (326.246 us; speedup 1.0000x reference)
//
#include <hip/hip_runtime.h>
#include <hip/hip_bf16.h>

#define NB   32
#define CH   64
#define LL   2048
#define OUTC 128

typedef float  f32x4  __attribute__((ext_vector_type(4)));
typedef short  s16x8  __attribute__((ext_vector_type(8)));
typedef short  s16x4  __attribute__((ext_vector_type(4)));
typedef unsigned short u16;

__device__ __forceinline__ u16 f2bf(float f) {
  unsigned int u = __builtin_bit_cast(unsigned int, f);
  u += 0x7FFFu + ((u >> 16) & 1u);           // RNE (scalar epilogue use)
  return (u16)(u >> 16);
}

__device__ __forceinline__ s16x8 pack8c(const float* v) {
  s16x8 r;
#pragma unroll
  for (int j = 0; j < 8; j += 2) {
    __hip_bfloat162 h = __float22bfloat162_rn(make_float2(v[j], v[j + 1]));
    short2 s;
    __builtin_memcpy(&s, &h, sizeof(s));
    r[j] = s.x; r[j + 1] = s.y;
  }
  return r;
}

__device__ __forceinline__ s16x4 pack4c(const f32x4& v) {
  s16x4 r;
  __hip_bfloat162 h0 = __float22bfloat162_rn(make_float2(v[0], v[1]));
  __hip_bfloat162 h1 = __float22bfloat162_rn(make_float2(v[2], v[3]));
  short2 s0, s1;
  __builtin_memcpy(&s0, &h0, sizeof(s0));
  __builtin_memcpy(&s1, &h1, sizeof(s1));
  r[0] = s0.x; r[1] = s0.y; r[2] = s1.x; r[3] = s1.y;
  return r;
}

// ---------------------------------------------------------------------------
// K0: x (fp32->bf16), W (fp32->bf16)
// ---------------------------------------------------------------------------
#define NX (NB * CH * LL)          // 4,194,304
#define NW (OUTC * 3 * CH)         // 24,576
__global__ __launch_bounds__(256)
void cvt_inputs(const float* __restrict__ x, const float* __restrict__ W,
                u16* __restrict__ xb, u16* __restrict__ Wb)
{
  const size_t t8 = ((size_t)blockIdx.x * 256 + threadIdx.x) * 8;
  if (t8 < NX) {
    float v[8];
    *(f32x4*)(v)     = *(const f32x4*)(x + t8);
    *(f32x4*)(v + 4) = *(const f32x4*)(x + t8 + 4);
    *(s16x8*)(xb + t8) = pack8c(v);
  } else if (t8 - NX < NW) {
    const size_t w8 = t8 - NX;
    float v[8];
    *(f32x4*)(v)     = *(const f32x4*)(W + w8);
    *(f32x4*)(v + 4) = *(const f32x4*)(W + w8 + 4);
    *(s16x8*)(Wb + w8) = pack8c(v);
  }
}

// ---------------------------------------------------------------------------
// K1: y1[n] = xb[n] * m[n]  (+ writes mP bf16 B-fragments for K2)
// SINGLE-WAVE blocks (64 thr), 32-col tiles, grid 2048 -> ~8 independent
// waves/CU, ZERO barriers. Quad-buffered gload_lds, distance-3 prefetch,
// counted vmcnt only (own-wave LDS dependency). Per-step issue
// [A:4][G:4]...[St:2]; steady vmcnt(30).
// ---------------------------------------------------------------------------
__global__ __launch_bounds__(64)
void prop1_pack(const u16* __restrict__ xb, const float* __restrict__ m,
                u16* __restrict__ y1, u16* __restrict__ mP)
{
  __shared__ float smem[4][32 * 32];   // 16 KiB quad-buffered 32x32 fp32 tile

  const int n    = blockIdx.x >> 6;
  const int lt   = blockIdx.x & 63;
  const int lane = threadIdx.x;
  const int l15  = lane & 15;
  const int g4   = lane >> 4;
  const int colb = lt * 32;

  const float* mn   = m + (size_t)n * LL * LL + colb;
  // chunk i: rows i*8+(lane>>3), cols (lane&7)*4 — 128B rows, lane*16B dest
  const float* gsrc = mn + (size_t)(lane >> 3) * LL + (lane & 7) * 4;
  const u16*   ap   = xb + (size_t)n * CH * LL + (size_t)l15 * LL + g4 * 8;
  u16* q0 = mP + (((size_t)n * 64 * LL + colb + l15) * 4 + g4) * 8; // + kb*65536, h*512
  u16* o  = y1 + (size_t)n * CH * LL + colb + l15;

  f32x4 acc[4][2];
#pragma unroll
  for (int f = 0; f < 4; ++f)
#pragma unroll
    for (int h = 0; h < 2; ++h)
#pragma unroll
      for (int r = 0; r < 4; ++r) acc[f][h][r] = 0.f;

  s16x8 aP[4], aQ[4];

#define ALOAD(R, KB)                                                          \
  { const u16* _ap = ap + (KB) * 32;                                          \
    _Pragma("unroll") for (int f = 0; f < 4; ++f)                             \
      R[f] = *(const s16x8*)(_ap + (size_t)(f * 16) * LL); }

#define GLOAD(BI, KB)                                                         \
  { float* _sb = smem[BI];                                                    \
    _Pragma("unroll") for (int i = 0; i < 4; ++i) {                           \
      const float* _g = gsrc + (size_t)((KB) * 32 + i * 8) * LL;              \
      __builtin_amdgcn_global_load_lds(                                       \
        (const __attribute__((address_space(1))) void*)_g,                    \
        (__attribute__((address_space(3))) void*)(_sb + i * 256),             \
        16, 0, 0); } }

  // prologue: A(0) first (oldest), then tiles 0,1,2
  ALOAD(aP, 0)
  __builtin_amdgcn_sched_barrier(0);
  GLOAD(0, 0) GLOAD(1, 1) GLOAD(2, 2)
  __builtin_amdgcn_sched_barrier(0);

  // step: [A(kb+1)][G(kb+3)] | vmcnt(VN) | ds_read tile kb, pack, St, MFMA
#define K1_STEP(KB, CUR, NXT, VN, LAST)                                       \
  {                                                                           \
    if (!(LAST)) {                                                            \
      ALOAD(NXT, ((KB) + 1 < 64 ? (KB) + 1 : 63))                             \
      __builtin_amdgcn_sched_barrier(0);                                      \
      GLOAD(((KB) + 3) & 3, ((KB) + 3 < 64 ? (KB) + 3 : 63))                  \
      __builtin_amdgcn_sched_barrier(0);                                      \
    }                                                                         \
    asm volatile("s_waitcnt vmcnt(" VN ")" ::: "memory");                     \
    __builtin_amdgcn_sched_barrier(0);                                        \
    const float* _t = smem[(KB) & 3] + l15;                                   \
    float _bv0[8], _bv1[8];                                                   \
    _Pragma("unroll") for (int j = 0; j < 8; ++j) {                           \
      _bv0[j] = _t[(g4 * 8 + j) * 32];                                        \
      _bv1[j] = _t[(g4 * 8 + j) * 32 + 16];                                   \
    }                                                                         \
    s16x8 _b0 = pack8c(_bv0), _b1 = pack8c(_bv1);                             \
    u16* _q = q0 + (size_t)(KB) * 65536;                                      \
    *(s16x8*)(_q)       = _b0;                                                \
    *(s16x8*)(_q + 512) = _b1;                                                \
    _Pragma("unroll") for (int f = 0; f < 4; ++f) {                           \
      acc[f][0] = __builtin_amdgcn_mfma_f32_16x16x32_bf16(CUR[f], _b0, acc[f][0], 0, 0, 0); \
      acc[f][1] = __builtin_amdgcn_mfma_f32_16x16x32_bf16(CUR[f], _b1, acc[f][1], 0, 0, 0); \
    }                                                                         \
  }

  K1_STEP(0, aP, aQ, "16", false)   // retire G0: G1+G2+A1+G3 = 16 newer
  K1_STEP(1, aQ, aP, "22", false)   // retire G1: +St0+A2+G4 = 22
  K1_STEP(2, aP, aQ, "28", false)   // retire G2: 28
#pragma unroll 1
  for (int kb = 3; kb < 63; kb += 2) {
    K1_STEP(kb,     aQ, aP, "30", false)
    K1_STEP(kb + 1, aP, aQ, "30", false)
  }
  K1_STEP(63, aQ, aP, "22", true)   // retire G63 (step 60): 22 newer

#pragma unroll
  for (int f = 0; f < 4; ++f)
#pragma unroll
    for (int r = 0; r < 4; ++r) {
      const int row = f * 16 + g4 * 4 + r;
      o[(size_t)row * LL]      = f2bf(acc[f][0][r]);
      o[(size_t)row * LL + 16] = f2bf(acc[f][1][r]);
    }
}

// ---------------------------------------------------------------------------
// K2: y2 = y1 * m (from mP) FUSED with projection. SINGLE-WAVE blocks,
// 32-col tiles, 3-stage register pipeline (prefetch distance 2).
// ---------------------------------------------------------------------------
__global__ __launch_bounds__(64)
void prop2_proj(const u16* __restrict__ y1, const u16* __restrict__ mP,
                const u16* __restrict__ xb, const u16* __restrict__ Wb,
                const float* __restrict__ bias, float* __restrict__ out)
{
  __shared__ u16 yT[32 * 72];   // col-major y2 tile: yT[col*72 + row], 4.5 KiB

  const int n    = blockIdx.x >> 6;
  const int lt   = blockIdx.x & 63;
  const int lane = threadIdx.x;
  const int l15  = lane & 15;
  const int g4   = lane >> 4;
  const int colb = lt * 32;

  const u16* mq = mP + (((size_t)n * 64 * LL + colb + l15) * 4 + g4) * 8;
  const u16* ap = y1 + (size_t)n * CH * LL + (size_t)l15 * LL + g4 * 8;

  f32x4 acc[4][2];
#pragma unroll
  for (int f = 0; f < 4; ++f)
#pragma unroll
    for (int h = 0; h < 2; ++h)
#pragma unroll
      for (int r = 0; r < 4; ++r) acc[f][h][r] = 0.f;

  s16x8 bA0, bA1, aA[4], bB0, bB1, aB[4], bC0, bC1, aC[4];

#define K2_LOAD(B0, B1, AV, KB)                                              \
  {                                                                          \
    const u16* _mq = mq + (size_t)(KB) * 65536;                              \
    B0 = *(const s16x8*)(_mq);                                               \
    B1 = *(const s16x8*)(_mq + 512);                                         \
    const u16* _ap = ap + (KB) * 32;                                         \
    _Pragma("unroll") for (int f = 0; f < 4; ++f)                            \
      AV[f] = *(const s16x8*)(_ap + (size_t)(f * 16) * LL);                  \
  }

#define K2_COMP(B0, B1, AV)                                                  \
  _Pragma("unroll") for (int f = 0; f < 4; ++f) {                            \
    acc[f][0] = __builtin_amdgcn_mfma_f32_16x16x32_bf16(AV[f], B0, acc[f][0], 0, 0, 0); \
    acc[f][1] = __builtin_amdgcn_mfma_f32_16x16x32_bf16(AV[f], B1, acc[f][1], 0, 0, 0); \
  }

  K2_LOAD(bA0, bA1, aA, 0)
  K2_LOAD(bB0, bB1, aB, 1)
  K2_LOAD(bC0, bC1, aC, 2)
#pragma unroll 1
  for (int kb = 0; kb < 63; kb += 3) {
    K2_COMP(bA0, bA1, aA)
    K2_LOAD(bA0, bA1, aA, (kb + 3 < 64 ? kb + 3 : 63))
    K2_COMP(bB0, bB1, aB)
    K2_LOAD(bB0, bB1, aB, (kb + 4 < 64 ? kb + 4 : 63))
    K2_COMP(bC0, bC1, aC)
    K2_LOAD(bC0, bC1, aC, (kb + 5 < 64 ? kb + 5 : 63))
  }
  K2_COMP(bA0, bA1, aA)   // kb = 63

  // ---- epilogue: y2 (acc) -> LDS col-major bf16 (single wave: no barrier) --
#pragma unroll
  for (int f = 0; f < 4; ++f)
#pragma unroll
    for (int h = 0; h < 2; ++h) {
      const int c = l15 + 16 * h;
      *(s16x4*)(&yT[c * 72 + f * 16 + g4 * 4]) = pack4c(acc[f][h]);
    }

  // ---- projection: out = Wb(128x192) * [xb;y1;y2] + b ----
  f32x4 acc2[8][2];
#pragma unroll
  for (int f = 0; f < 8; ++f)
#pragma unroll
    for (int h = 0; h < 2; ++h)
#pragma unroll
      for (int r = 0; r < 4; ++r) acc2[f][h][r] = 0.f;

  const size_t cb = (size_t)n * CH * LL + colb + l15;
  const u16* xp  = xb + cb + (size_t)(g4 * 8) * LL;
  const u16* y1p = y1 + cb + (size_t)(g4 * 8) * LL;
  const u16* wq  = Wb + (size_t)l15 * 192 + g4 * 8;

#pragma unroll
  for (int kc = 0; kc < 6; ++kc) {
    const int k0 = kc * 32;
    s16x8 b0, b1;
    if (kc < 4) {
      const u16* src = (kc < 2) ? (xp + (size_t)k0 * LL)
                                : (y1p + (size_t)(k0 - 64) * LL);
#pragma unroll
      for (int j = 0; j < 8; ++j) {
        b0[j] = (short)src[(size_t)j * LL];
        b1[j] = (short)src[(size_t)j * LL + 16];
      }
    } else {
      const int rb = (kc - 4) * 32 + g4 * 8;
      b0 = *(const s16x8*)(&yT[l15 * 72 + rb]);
      b1 = *(const s16x8*)(&yT[(l15 + 16) * 72 + rb]);
    }
#pragma unroll
    for (int f = 0; f < 8; ++f) {
      s16x8 af = *(const s16x8*)(wq + (size_t)(f * 16) * 192 + k0);
      acc2[f][0] = __builtin_amdgcn_mfma_f32_16x16x32_bf16(af, b0, acc2[f][0], 0, 0, 0);
      acc2[f][1] = __builtin_amdgcn_mfma_f32_16x16x32_bf16(af, b1, acc2[f][1], 0, 0, 0);
    }
  }

  float* op = out + (size_t)n * OUTC * LL + colb + l15;
#pragma unroll
  for (int f = 0; f < 8; ++f)
#pragma unroll
    for (int r = 0; r < 4; ++r) {
      const int row = f * 16 + g4 * 4 + r;
      op[(size_t)row * LL]      = acc2[f][0][r] + bias[row];
      op[(size_t)row * LL + 16] = acc2[f][1][r] + bias[row];
    }
}

extern "C" void kernel_launch(void* const* d_in, const int* in_sizes, int n_in,
                              void* d_out, int out_size, void* d_ws, size_t ws_size,
                              hipStream_t stream)
{
  const float* x = (const float*)d_in[0];
  const float* m = (const float*)d_in[1];
  const float* W = (const float*)d_in[2];
  const float* b = (const float*)d_in[3];
  float* out = (float*)d_out;

  // workspace layout (u16 elems): y1 | xb | Wb | mP
  u16* y1 = (u16*)d_ws;                          //  8 MiB
  u16* xb = y1 + (size_t)NB * CH * LL;           //  8 MiB
  u16* Wb = xb + (size_t)NB * CH * LL;           // 48 KiB
  u16* mP = (u16*)((char*)d_ws + (25u << 20));   // 256 MiB, 1 MiB-aligned

  cvt_inputs<<<dim3(2060), dim3(256), 0, stream>>>(x, W, xb, Wb);
  prop1_pack<<<dim3(NB * 64), dim3(64), 0, stream>>>(xb, m, y1, mP);
  prop2_proj<<<dim3(NB * 64), dim3(64), 0, stream>>>(y1, mP, xb, Wb, b, out);
}

// Round 13
// 271.338 us; speedup vs baseline: 1.2024x; 1.2024x over previous
//
#include <hip/hip_runtime.h>
#include <hip/hip_bf16.h>

#define NB   32
#define CH   64
#define LL   2048
#define OUTC 128

typedef float  f32x4  __attribute__((ext_vector_type(4)));
typedef short  s16x8  __attribute__((ext_vector_type(8)));
typedef short  s16x4  __attribute__((ext_vector_type(4)));
typedef unsigned short u16;

__device__ __forceinline__ u16 f2bf(float f) {
  unsigned int u = __builtin_bit_cast(unsigned int, f);
  u += 0x7FFFu + ((u >> 16) & 1u);           // RNE (scalar epilogue use)
  return (u16)(u >> 16);
}

__device__ __forceinline__ s16x8 pack8c(const float* v) {
  s16x8 r;
#pragma unroll
  for (int j = 0; j < 8; j += 2) {
    __hip_bfloat162 h = __float22bfloat162_rn(make_float2(v[j], v[j + 1]));
    short2 s;
    __builtin_memcpy(&s, &h, sizeof(s));
    r[j] = s.x; r[j + 1] = s.y;
  }
  return r;
}

__device__ __forceinline__ s16x4 pack4c(const f32x4& v) {
  s16x4 r;
  __hip_bfloat162 h0 = __float22bfloat162_rn(make_float2(v[0], v[1]));
  __hip_bfloat162 h1 = __float22bfloat162_rn(make_float2(v[2], v[3]));
  short2 s0, s1;
  __builtin_memcpy(&s0, &h0, sizeof(s0));
  __builtin_memcpy(&s1, &h1, sizeof(s1));
  r[0] = s0.x; r[1] = s0.y; r[2] = s1.x; r[3] = s1.y;
  return r;
}

// ---------------------------------------------------------------------------
// K0: x (fp32->bf16), W (fp32->bf16)
// ---------------------------------------------------------------------------
#define NX (NB * CH * LL)          // 4,194,304
#define NW (OUTC * 3 * CH)         // 24,576
__global__ __launch_bounds__(256)
void cvt_inputs(const float* __restrict__ x, const float* __restrict__ W,
                u16* __restrict__ xb, u16* __restrict__ Wb)
{
  const size_t t8 = ((size_t)blockIdx.x * 256 + threadIdx.x) * 8;
  if (t8 < NX) {
    float v[8];
    *(f32x4*)(v)     = *(const f32x4*)(x + t8);
    *(f32x4*)(v + 4) = *(const f32x4*)(x + t8 + 4);
    *(s16x8*)(xb + t8) = pack8c(v);
  } else if (t8 - NX < NW) {
    const size_t w8 = t8 - NX;
    float v[8];
    *(f32x4*)(v)     = *(const f32x4*)(W + w8);
    *(f32x4*)(v + 4) = *(const f32x4*)(W + w8 + 4);
    *(s16x8*)(Wb + w8) = pack8c(v);
  }
}

// ---------------------------------------------------------------------------
// K1: y1[n] = xb[n] * m[n]  (+ writes mP bf16 B-fragments for K2)
// 256-thr / 128-col tiles (the proven geometry), but TRIPLE-buffered (48 KiB
// LDS) distance-2 pipeline -> 3 blocks/CU = 12 waves/CU (was 2/8).
// Per-step issue [A:4][G:4]...[St:2]; end-of-step wait gates next tile:
// vmcnt steady = 12 (one tile + next-A + stores stay in flight).
// ---------------------------------------------------------------------------
__global__ __launch_bounds__(256, 3)
void prop1_pack(const u16* __restrict__ xb, const float* __restrict__ m,
                u16* __restrict__ y1, u16* __restrict__ mP)
{
  __shared__ float smem[3][32 * 128];   // 48 KiB triple-buffered 32x128 fp32

  const int n    = blockIdx.x >> 4;
  const int lt   = blockIdx.x & 15;
  const int tid  = threadIdx.x;
  const int wave = tid >> 6;
  const int lane = tid & 63;
  const int l15  = lane & 15;
  const int g4   = lane >> 4;
  const int colb = lt * 128 + wave * 32;

  const float* mn   = m + (size_t)n * LL * LL + lt * 128;
  const float* gsrc = mn + (size_t)(wave * 8 + (lane >> 5)) * LL + (lane & 31) * 4;
  const u16*   ap   = xb + (size_t)n * CH * LL + (size_t)l15 * LL + g4 * 8;
  u16* q0 = mP + (((size_t)n * 64 * LL + colb + l15) * 4 + g4) * 8; // + kb*65536, h*512
  u16* o  = y1 + (size_t)n * CH * LL + colb + l15;

  f32x4 acc[4][2];
#pragma unroll
  for (int f = 0; f < 4; ++f)
#pragma unroll
    for (int h = 0; h < 2; ++h)
#pragma unroll
      for (int r = 0; r < 4; ++r) acc[f][h][r] = 0.f;

  s16x8 aP[4], aQ[4];

#define ALOAD(R, KB)                                                          \
  { const u16* _ap = ap + (KB) * 32;                                          \
    _Pragma("unroll") for (int f = 0; f < 4; ++f)                             \
      R[f] = *(const s16x8*)(_ap + (size_t)(f * 16) * LL); }

#define GLOAD(BI, KB)                                                         \
  { float* _sb = smem[BI];                                                    \
    _Pragma("unroll") for (int i = 0; i < 4; ++i) {                           \
      const float* _g = gsrc + (size_t)((KB) * 32 + i * 2) * LL;              \
      __builtin_amdgcn_global_load_lds(                                       \
        (const __attribute__((address_space(1))) void*)_g,                    \
        (__attribute__((address_space(3))) void*)(_sb + (wave * 4 + i) * 256),\
        16, 0, 0); } }

  // prologue: A0 (oldest), tiles 0,1; gate tile 0 (only G1 newer than G0)
  ALOAD(aP, 0)
  __builtin_amdgcn_sched_barrier(0);
  GLOAD(0, 0) GLOAD(1, 1)
  __builtin_amdgcn_sched_barrier(0);
  asm volatile("s_waitcnt vmcnt(4)" ::: "memory");
  __builtin_amdgcn_s_barrier();
  __builtin_amdgcn_sched_barrier(0);

  // step KB: issue A(KB+1), G(KB+2) -> buffer GI=(KB+2)%3; compute tile KB
  // from buffer BI=KB%3; end wait vmcnt(VN)+barrier gates tile KB+1.
#define K1_STEP(KB, CUR, NXT, GI, BI, VN, DOA, DOG, DOBAR)                    \
  {                                                                           \
    if (DOA) {                                                                \
      ALOAD(NXT, (KB) + 1)                                                    \
      __builtin_amdgcn_sched_barrier(0);                                      \
    }                                                                         \
    if (DOG) {                                                                \
      GLOAD(GI, (KB) + 2)                                                     \
      __builtin_amdgcn_sched_barrier(0);                                      \
    }                                                                         \
    const float* _t = smem[BI] + wave * 32 + l15;                             \
    float _bv0[8], _bv1[8];                                                   \
    _Pragma("unroll") for (int j = 0; j < 8; ++j) {                           \
      _bv0[j] = _t[(g4 * 8 + j) * 128];                                       \
      _bv1[j] = _t[(g4 * 8 + j) * 128 + 16];                                  \
    }                                                                         \
    s16x8 _b0 = pack8c(_bv0), _b1 = pack8c(_bv1);                             \
    u16* _q = q0 + (size_t)(KB) * 65536;                                      \
    *(s16x8*)(_q)       = _b0;                                                \
    *(s16x8*)(_q + 512) = _b1;                                                \
    _Pragma("unroll") for (int f = 0; f < 4; ++f) {                           \
      acc[f][0] = __builtin_amdgcn_mfma_f32_16x16x32_bf16(CUR[f], _b0, acc[f][0], 0, 0, 0); \
      acc[f][1] = __builtin_amdgcn_mfma_f32_16x16x32_bf16(CUR[f], _b1, acc[f][1], 0, 0, 0); \
    }                                                                         \
    if (DOBAR) {                                                              \
      __builtin_amdgcn_sched_barrier(0);                                      \
      asm volatile("s_waitcnt vmcnt(" VN ")" ::: "memory");                   \
      __builtin_amdgcn_s_barrier();                                           \
      __builtin_amdgcn_sched_barrier(0);                                      \
    }                                                                         \
  }

  K1_STEP(0, aP, aQ, 2, 0, "10", 1, 1, 1)   // gate G1: A1+G2+St0 = 10 newer
#pragma unroll 1
  for (int kb = 1; kb <= 55; kb += 6) {     // steps 1..60, steady vmcnt(12)
    K1_STEP(kb,     aQ, aP, 0, 1, "12", 1, 1, 1)
    K1_STEP(kb + 1, aP, aQ, 1, 2, "12", 1, 1, 1)
    K1_STEP(kb + 2, aQ, aP, 2, 0, "12", 1, 1, 1)
    K1_STEP(kb + 3, aP, aQ, 0, 1, "12", 1, 1, 1)
    K1_STEP(kb + 4, aQ, aP, 1, 2, "12", 1, 1, 1)
    K1_STEP(kb + 5, aP, aQ, 2, 0, "12", 1, 1, 1)
  }
  K1_STEP(61, aQ, aP, 0, 1, "12", 1, 1, 1)  // issues A62, G63
  K1_STEP(62, aP, aQ, 0, 2, "8",  1, 0, 1)  // issues A63; gate G63: St61+A63+St62 = 8
  K1_STEP(63, aQ, aP, 0, 0, "0",  0, 0, 0)  // compute only

#pragma unroll
  for (int f = 0; f < 4; ++f)
#pragma unroll
    for (int r = 0; r < 4; ++r) {
      const int row = f * 16 + g4 * 4 + r;
      o[(size_t)row * LL]      = f2bf(acc[f][0][r]);
      o[(size_t)row * LL + 16] = f2bf(acc[f][1][r]);
    }
}

// ---------------------------------------------------------------------------
// K2: y2 = y1 * m (from mP, reversed kb) FUSED with projection.
// Occupancy bound raised to 3 blocks/CU (LDS is only 18 KiB).
// ---------------------------------------------------------------------------
__global__ __launch_bounds__(256, 3)
void prop2_proj(const u16* __restrict__ y1, const u16* __restrict__ mP,
                const u16* __restrict__ xb, const u16* __restrict__ Wb,
                const float* __restrict__ bias, float* __restrict__ out)
{
  __shared__ u16 yT[128 * 72];   // col-major y2 tile: yT[col*72 + row], 18 KiB

  const int n    = blockIdx.x >> 4;
  const int lt   = blockIdx.x & 15;
  const int tid  = threadIdx.x;
  const int wave = tid >> 6;
  const int lane = tid & 63;
  const int l15  = lane & 15;
  const int g4   = lane >> 4;
  const int colb = lt * 128 + wave * 32;

  const u16* mq = mP + (((size_t)n * 64 * LL + colb + l15) * 4 + g4) * 8;
  const u16* ap = y1 + (size_t)n * CH * LL + (size_t)l15 * LL + g4 * 8;

  f32x4 acc[4][2];
#pragma unroll
  for (int f = 0; f < 4; ++f)
#pragma unroll
    for (int h = 0; h < 2; ++h)
#pragma unroll
      for (int r = 0; r < 4; ++r) acc[f][h][r] = 0.f;

  s16x8 bA0, bA1, bB0, bB1, aA[4], aB[4];

#define K2_LOAD(B0, B1, AV, KB)                                              \
  {                                                                          \
    const u16* _mq = mq + (size_t)(KB) * 65536;                              \
    B0 = *(const s16x8*)(_mq);                                               \
    B1 = *(const s16x8*)(_mq + 512);                                         \
    const u16* _ap = ap + (KB) * 32;                                         \
    _Pragma("unroll") for (int f = 0; f < 4; ++f)                            \
      AV[f] = *(const s16x8*)(_ap + (size_t)(f * 16) * LL);                  \
  }

#define K2_COMP(B0, B1, AV)                                                  \
  _Pragma("unroll") for (int f = 0; f < 4; ++f) {                            \
    acc[f][0] = __builtin_amdgcn_mfma_f32_16x16x32_bf16(AV[f], B0, acc[f][0], 0, 0, 0); \
    acc[f][1] = __builtin_amdgcn_mfma_f32_16x16x32_bf16(AV[f], B1, acc[f][1], 0, 0, 0); \
  }

  K2_LOAD(bA0, bA1, aA, 63)
#pragma unroll 1
  for (int kb = 63; kb >= 1; kb -= 2) {
    K2_LOAD(bB0, bB1, aB, kb - 1)
    K2_COMP(bA0, bA1, aA)
    if (kb - 2 >= 0) K2_LOAD(bA0, bA1, aA, kb - 2)
    K2_COMP(bB0, bB1, aB)
  }

  // ---- epilogue: y2 (acc) -> LDS col-major bf16 ----
#pragma unroll
  for (int f = 0; f < 4; ++f)
#pragma unroll
    for (int h = 0; h < 2; ++h) {
      const int c = wave * 32 + l15 + 16 * h;
      *(s16x4*)(&yT[c * 72 + f * 16 + g4 * 4]) = pack4c(acc[f][h]);
    }
  __syncthreads();

  // ---- projection: out = Wb(128x192) * [xb;y1;y2] + b ----
  f32x4 acc2[8][2];
#pragma unroll
  for (int f = 0; f < 8; ++f)
#pragma unroll
    for (int h = 0; h < 2; ++h)
#pragma unroll
      for (int r = 0; r < 4; ++r) acc2[f][h][r] = 0.f;

  const size_t cb = (size_t)n * CH * LL + colb + l15;
  const u16* xp  = xb + cb + (size_t)(g4 * 8) * LL;
  const u16* y1p = y1 + cb + (size_t)(g4 * 8) * LL;
  const u16* wq  = Wb + (size_t)l15 * 192 + g4 * 8;

#pragma unroll
  for (int kc = 0; kc < 6; ++kc) {
    const int k0 = kc * 32;
    s16x8 b0, b1;
    if (kc < 4) {
      const u16* src = (kc < 2) ? (xp + (size_t)k0 * LL)
                                : (y1p + (size_t)(k0 - 64) * LL);
#pragma unroll
      for (int j = 0; j < 8; ++j) {
        b0[j] = (short)src[(size_t)j * LL];
        b1[j] = (short)src[(size_t)j * LL + 16];
      }
    } else {
      const int rb = (kc - 4) * 32 + g4 * 8;
      b0 = *(const s16x8*)(&yT[(wave * 32 + l15) * 72 + rb]);
      b1 = *(const s16x8*)(&yT[(wave * 32 + l15 + 16) * 72 + rb]);
    }
#pragma unroll
    for (int f = 0; f < 8; ++f) {
      s16x8 af = *(const s16x8*)(wq + (size_t)(f * 16) * 192 + k0);
      acc2[f][0] = __builtin_amdgcn_mfma_f32_16x16x32_bf16(af, b0, acc2[f][0], 0, 0, 0);
      acc2[f][1] = __builtin_amdgcn_mfma_f32_16x16x32_bf16(af, b1, acc2[f][1], 0, 0, 0);
    }
  }

  float* op = out + (size_t)n * OUTC * LL + colb + l15;
#pragma unroll
  for (int f = 0; f < 8; ++f)
#pragma unroll
    for (int r = 0; r < 4; ++r) {
      const int row = f * 16 + g4 * 4 + r;
      op[(size_t)row * LL]      = acc2[f][0][r] + bias[row];
      op[(size_t)row * LL + 16] = acc2[f][1][r] + bias[row];
    }
}

extern "C" void kernel_launch(void* const* d_in, const int* in_sizes, int n_in,
                              void* d_out, int out_size, void* d_ws, size_t ws_size,
                              hipStream_t stream)
{
  const float* x = (const float*)d_in[0];
  const float* m = (const float*)d_in[1];
  const float* W = (const float*)d_in[2];
  const float* b = (const float*)d_in[3];
  float* out = (float*)d_out;

  // workspace layout (u16 elems): y1 | xb | Wb | mP
  u16* y1 = (u16*)d_ws;                          //  8 MiB
  u16* xb = y1 + (size_t)NB * CH * LL;           //  8 MiB
  u16* Wb = xb + (size_t)NB * CH * LL;           // 48 KiB
  u16* mP = (u16*)((char*)d_ws + (25u << 20));   // 256 MiB, 1 MiB-aligned

  cvt_inputs<<<dim3(2060), dim3(256), 0, stream>>>(x, W, xb, Wb);
  prop1_pack<<<dim3(NB * 16), dim3(256), 0, stream>>>(xb, m, y1, mP);
  prop2_proj<<<dim3(NB * 16), dim3(256), 0, stream>>>(y1, mP, xb, Wb, b, out);
}

// Round 14
// 262.514 us; speedup vs baseline: 1.2428x; 1.0336x over previous
//
#include <hip/hip_runtime.h>
#include <hip/hip_bf16.h>

#define NB   32
#define CH   64
#define LL   2048
#define OUTC 128

typedef float  f32x4  __attribute__((ext_vector_type(4)));
typedef short  s16x8  __attribute__((ext_vector_type(8)));
typedef short  s16x4  __attribute__((ext_vector_type(4)));
typedef unsigned short u16;

__device__ __forceinline__ u16 f2bf(float f) {
  unsigned int u = __builtin_bit_cast(unsigned int, f);
  u += 0x7FFFu + ((u >> 16) & 1u);           // RNE (scalar epilogue use)
  return (u16)(u >> 16);
}

__device__ __forceinline__ s16x8 pack8c(const float* v) {
  s16x8 r;
#pragma unroll
  for (int j = 0; j < 8; j += 2) {
    __hip_bfloat162 h = __float22bfloat162_rn(make_float2(v[j], v[j + 1]));
    short2 s;
    __builtin_memcpy(&s, &h, sizeof(s));
    r[j] = s.x; r[j + 1] = s.y;
  }
  return r;
}

__device__ __forceinline__ s16x4 pack4c(const f32x4& v) {
  s16x4 r;
  __hip_bfloat162 h0 = __float22bfloat162_rn(make_float2(v[0], v[1]));
  __hip_bfloat162 h1 = __float22bfloat162_rn(make_float2(v[2], v[3]));
  short2 s0, s1;
  __builtin_memcpy(&s0, &h0, sizeof(s0));
  __builtin_memcpy(&s1, &h1, sizeof(s1));
  r[0] = s0.x; r[1] = s0.y; r[2] = s1.x; r[3] = s1.y;
  return r;
}

// ---------------------------------------------------------------------------
// K0: x (fp32->bf16), W (fp32->bf16)
// ---------------------------------------------------------------------------
#define NX (NB * CH * LL)          // 4,194,304
#define NW (OUTC * 3 * CH)         // 24,576
__global__ __launch_bounds__(256)
void cvt_inputs(const float* __restrict__ x, const float* __restrict__ W,
                u16* __restrict__ xb, u16* __restrict__ Wb)
{
  const size_t t8 = ((size_t)blockIdx.x * 256 + threadIdx.x) * 8;
  if (t8 < NX) {
    float v[8];
    *(f32x4*)(v)     = *(const f32x4*)(x + t8);
    *(f32x4*)(v + 4) = *(const f32x4*)(x + t8 + 4);
    *(s16x8*)(xb + t8) = pack8c(v);
  } else if (t8 - NX < NW) {
    const size_t w8 = t8 - NX;
    float v[8];
    *(f32x4*)(v)     = *(const f32x4*)(W + w8);
    *(f32x4*)(v + 4) = *(const f32x4*)(W + w8 + 4);
    *(s16x8*)(Wb + w8) = pack8c(v);
  }
}

// ---------------------------------------------------------------------------
// K1: y1[n] = xb[n] * m[n]  (+ writes mP bf16 B-fragments for K2)
// 256-COL tiles: each global_load_lds fetches a FULL CONTIGUOUS 1 KB row of
// the 32x256 tile (vs 512 B at 128-col) — tests the DRAM-granularity trend
// 32col=326 / 64col=299 / 128col=270 us. Grid 256 (1 block/CU), 96 KiB LDS
// triple-buffer, distance-2, counted vmcnt + raw s_barrier.
// Per-step issue [A:4][G:8][St:4]; steady vmcnt(20).
// ---------------------------------------------------------------------------
__global__ __launch_bounds__(256)
void prop1_pack(const u16* __restrict__ xb, const float* __restrict__ m,
                u16* __restrict__ y1, u16* __restrict__ mP)
{
  __shared__ float smem[3][32 * 256];   // 96 KiB triple-buffered 32x256 fp32

  const int n    = blockIdx.x >> 3;
  const int lt   = blockIdx.x & 7;
  const int tid  = threadIdx.x;
  const int wave = tid >> 6;
  const int lane = tid & 63;
  const int l15  = lane & 15;
  const int g4   = lane >> 4;
  const int colb = lt * 256 + wave * 64;

  const float* mn   = m + (size_t)n * LL * LL + lt * 256;
  // chunk i covers tile row 4*i + wave (one full 1 KB row per instruction)
  const float* gsrc = mn + (size_t)wave * LL + lane * 4;
  const u16*   ap   = xb + (size_t)n * CH * LL + (size_t)l15 * LL + g4 * 8;
  u16* q0 = mP + (((size_t)n * 64 * LL + colb + l15) * 4 + g4) * 8; // + kb*65536, h*512
  u16* o  = y1 + (size_t)n * CH * LL + colb + l15;

  f32x4 acc[4][4];
#pragma unroll
  for (int f = 0; f < 4; ++f)
#pragma unroll
    for (int h = 0; h < 4; ++h)
#pragma unroll
      for (int r = 0; r < 4; ++r) acc[f][h][r] = 0.f;

  s16x8 aP[4], aQ[4];

#define ALOAD(R, KB)                                                          \
  { const u16* _ap = ap + (KB) * 32;                                          \
    _Pragma("unroll") for (int f = 0; f < 4; ++f)                             \
      R[f] = *(const s16x8*)(_ap + (size_t)(f * 16) * LL); }

#define GLOAD(BI, KB)                                                         \
  { float* _sb = smem[BI];                                                    \
    _Pragma("unroll") for (int i = 0; i < 8; ++i) {                           \
      const float* _g = gsrc + (size_t)((KB) * 32 + i * 4) * LL;              \
      __builtin_amdgcn_global_load_lds(                                       \
        (const __attribute__((address_space(1))) void*)_g,                    \
        (__attribute__((address_space(3))) void*)(_sb + i * 1024 + wave * 256),\
        16, 0, 0); } }

  // prologue: A0 (oldest), tiles 0,1; gate tile 0 (only G1:8 newer)
  ALOAD(aP, 0)
  __builtin_amdgcn_sched_barrier(0);
  GLOAD(0, 0) GLOAD(1, 1)
  __builtin_amdgcn_sched_barrier(0);
  asm volatile("s_waitcnt vmcnt(8)" ::: "memory");
  __builtin_amdgcn_s_barrier();
  __builtin_amdgcn_sched_barrier(0);

  // step KB: issue A(KB+1), G(KB+2)->buf GI; compute tile KB from buf BI;
  // end wait vmcnt(VN)+barrier gates tile KB+1.
#define K1_STEP(KB, CUR, NXT, GI, BI, VN, DOA, DOG, DOBAR)                    \
  {                                                                           \
    if (DOA) {                                                                \
      ALOAD(NXT, (KB) + 1)                                                    \
      __builtin_amdgcn_sched_barrier(0);                                      \
    }                                                                         \
    if (DOG) {                                                                \
      GLOAD(GI, (KB) + 2)                                                     \
      __builtin_amdgcn_sched_barrier(0);                                      \
    }                                                                         \
    const float* _t = smem[BI] + wave * 64 + l15;                             \
    s16x8 _b[4];                                                              \
    _Pragma("unroll") for (int h = 0; h < 4; ++h) {                           \
      float _bv[8];                                                           \
      _Pragma("unroll") for (int j = 0; j < 8; ++j)                           \
        _bv[j] = _t[(g4 * 8 + j) * 256 + h * 16];                             \
      _b[h] = pack8c(_bv);                                                    \
    }                                                                         \
    u16* _q = q0 + (size_t)(KB) * 65536;                                      \
    _Pragma("unroll") for (int h = 0; h < 4; ++h)                             \
      *(s16x8*)(_q + h * 512) = _b[h];                                        \
    _Pragma("unroll") for (int f = 0; f < 4; ++f)                             \
      _Pragma("unroll") for (int h = 0; h < 4; ++h)                           \
        acc[f][h] = __builtin_amdgcn_mfma_f32_16x16x32_bf16(CUR[f], _b[h], acc[f][h], 0, 0, 0); \
    if (DOBAR) {                                                              \
      __builtin_amdgcn_sched_barrier(0);                                      \
      asm volatile("s_waitcnt vmcnt(" VN ")" ::: "memory");                   \
      __builtin_amdgcn_s_barrier();                                           \
      __builtin_amdgcn_sched_barrier(0);                                      \
    }                                                                         \
  }

  K1_STEP(0, aP, aQ, 2, 0, "16", 1, 1, 1)   // gate G1: A1+G2+St0 = 16 newer
#pragma unroll 1
  for (int kb = 1; kb <= 55; kb += 6) {     // steps 1..60, steady vmcnt(20)
    K1_STEP(kb,     aQ, aP, 0, 1, "20", 1, 1, 1)
    K1_STEP(kb + 1, aP, aQ, 1, 2, "20", 1, 1, 1)
    K1_STEP(kb + 2, aQ, aP, 2, 0, "20", 1, 1, 1)
    K1_STEP(kb + 3, aP, aQ, 0, 1, "20", 1, 1, 1)
    K1_STEP(kb + 4, aQ, aP, 1, 2, "20", 1, 1, 1)
    K1_STEP(kb + 5, aP, aQ, 2, 0, "20", 1, 1, 1)
  }
  K1_STEP(61, aQ, aP, 0, 1, "20", 1, 1, 1)  // issues A62, G63->buf0
  K1_STEP(62, aP, aQ, 0, 2, "12", 1, 0, 1)  // issues A63; gate G63: St61+A63+St62 = 12
  K1_STEP(63, aQ, aP, 0, 0, "0",  0, 0, 0)  // compute only

#pragma unroll
  for (int f = 0; f < 4; ++f)
#pragma unroll
    for (int h = 0; h < 4; ++h)
#pragma unroll
      for (int r = 0; r < 4; ++r) {
        const int row = f * 16 + g4 * 4 + r;
        o[(size_t)row * LL + h * 16] = f2bf(acc[f][h][r]);
      }
}

// ---------------------------------------------------------------------------
// K2: y2 = y1 * m (from mP, reversed kb) FUSED with projection.
// (unchanged from the 271 us kernel)
// ---------------------------------------------------------------------------
__global__ __launch_bounds__(256, 3)
void prop2_proj(const u16* __restrict__ y1, const u16* __restrict__ mP,
                const u16* __restrict__ xb, const u16* __restrict__ Wb,
                const float* __restrict__ bias, float* __restrict__ out)
{
  __shared__ u16 yT[128 * 72];   // col-major y2 tile: yT[col*72 + row], 18 KiB

  const int n    = blockIdx.x >> 4;
  const int lt   = blockIdx.x & 15;
  const int tid  = threadIdx.x;
  const int wave = tid >> 6;
  const int lane = tid & 63;
  const int l15  = lane & 15;
  const int g4   = lane >> 4;
  const int colb = lt * 128 + wave * 32;

  const u16* mq = mP + (((size_t)n * 64 * LL + colb + l15) * 4 + g4) * 8;
  const u16* ap = y1 + (size_t)n * CH * LL + (size_t)l15 * LL + g4 * 8;

  f32x4 acc[4][2];
#pragma unroll
  for (int f = 0; f < 4; ++f)
#pragma unroll
    for (int h = 0; h < 2; ++h)
#pragma unroll
      for (int r = 0; r < 4; ++r) acc[f][h][r] = 0.f;

  s16x8 bA0, bA1, bB0, bB1, aA[4], aB[4];

#define K2_LOAD(B0, B1, AV, KB)                                              \
  {                                                                          \
    const u16* _mq = mq + (size_t)(KB) * 65536;                              \
    B0 = *(const s16x8*)(_mq);                                               \
    B1 = *(const s16x8*)(_mq + 512);                                         \
    const u16* _ap = ap + (KB) * 32;                                         \
    _Pragma("unroll") for (int f = 0; f < 4; ++f)                            \
      AV[f] = *(const s16x8*)(_ap + (size_t)(f * 16) * LL);                  \
  }

#define K2_COMP(B0, B1, AV)                                                  \
  _Pragma("unroll") for (int f = 0; f < 4; ++f) {                            \
    acc[f][0] = __builtin_amdgcn_mfma_f32_16x16x32_bf16(AV[f], B0, acc[f][0], 0, 0, 0); \
    acc[f][1] = __builtin_amdgcn_mfma_f32_16x16x32_bf16(AV[f], B1, acc[f][1], 0, 0, 0); \
  }

  K2_LOAD(bA0, bA1, aA, 63)
#pragma unroll 1
  for (int kb = 63; kb >= 1; kb -= 2) {
    K2_LOAD(bB0, bB1, aB, kb - 1)
    K2_COMP(bA0, bA1, aA)
    if (kb - 2 >= 0) K2_LOAD(bA0, bA1, aA, kb - 2)
    K2_COMP(bB0, bB1, aB)
  }

  // ---- epilogue: y2 (acc) -> LDS col-major bf16 ----
#pragma unroll
  for (int f = 0; f < 4; ++f)
#pragma unroll
    for (int h = 0; h < 2; ++h) {
      const int c = wave * 32 + l15 + 16 * h;
      *(s16x4*)(&yT[c * 72 + f * 16 + g4 * 4]) = pack4c(acc[f][h]);
    }
  __syncthreads();

  // ---- projection: out = Wb(128x192) * [xb;y1;y2] + b ----
  f32x4 acc2[8][2];
#pragma unroll
  for (int f = 0; f < 8; ++f)
#pragma unroll
    for (int h = 0; h < 2; ++h)
#pragma unroll
      for (int r = 0; r < 4; ++r) acc2[f][h][r] = 0.f;

  const size_t cb = (size_t)n * CH * LL + colb + l15;
  const u16* xp  = xb + cb + (size_t)(g4 * 8) * LL;
  const u16* y1p = y1 + cb + (size_t)(g4 * 8) * LL;
  const u16* wq  = Wb + (size_t)l15 * 192 + g4 * 8;

#pragma unroll
  for (int kc = 0; kc < 6; ++kc) {
    const int k0 = kc * 32;
    s16x8 b0, b1;
    if (kc < 4) {
      const u16* src = (kc < 2) ? (xp + (size_t)k0 * LL)
                                : (y1p + (size_t)(k0 - 64) * LL);
#pragma unroll
      for (int j = 0; j < 8; ++j) {
        b0[j] = (short)src[(size_t)j * LL];
        b1[j] = (short)src[(size_t)j * LL + 16];
      }
    } else {
      const int rb = (kc - 4) * 32 + g4 * 8;
      b0 = *(const s16x8*)(&yT[(wave * 32 + l15) * 72 + rb]);
      b1 = *(const s16x8*)(&yT[(wave * 32 + l15 + 16) * 72 + rb]);
    }
#pragma unroll
    for (int f = 0; f < 8; ++f) {
      s16x8 af = *(const s16x8*)(wq + (size_t)(f * 16) * 192 + k0);
      acc2[f][0] = __builtin_amdgcn_mfma_f32_16x16x32_bf16(af, b0, acc2[f][0], 0, 0, 0);
      acc2[f][1] = __builtin_amdgcn_mfma_f32_16x16x32_bf16(af, b1, acc2[f][1], 0, 0, 0);
    }
  }

  float* op = out + (size_t)n * OUTC * LL + colb + l15;
#pragma unroll
  for (int f = 0; f < 8; ++f)
#pragma unroll
    for (int r = 0; r < 4; ++r) {
      const int row = f * 16 + g4 * 4 + r;
      op[(size_t)row * LL]      = acc2[f][0][r] + bias[row];
      op[(size_t)row * LL + 16] = acc2[f][1][r] + bias[row];
    }
}

extern "C" void kernel_launch(void* const* d_in, const int* in_sizes, int n_in,
                              void* d_out, int out_size, void* d_ws, size_t ws_size,
                              hipStream_t stream)
{
  const float* x = (const float*)d_in[0];
  const float* m = (const float*)d_in[1];
  const float* W = (const float*)d_in[2];
  const float* b = (const float*)d_in[3];
  float* out = (float*)d_out;

  // workspace layout (u16 elems): y1 | xb | Wb | mP
  u16* y1 = (u16*)d_ws;                          //  8 MiB
  u16* xb = y1 + (size_t)NB * CH * LL;           //  8 MiB
  u16* Wb = xb + (size_t)NB * CH * LL;           // 48 KiB
  u16* mP = (u16*)((char*)d_ws + (25u << 20));   // 256 MiB, 1 MiB-aligned

  cvt_inputs<<<dim3(2060), dim3(256), 0, stream>>>(x, W, xb, Wb);
  prop1_pack<<<dim3(NB * 8), dim3(256), 0, stream>>>(xb, m, y1, mP);
  prop2_proj<<<dim3(NB * 16), dim3(256), 0, stream>>>(y1, mP, xb, Wb, b, out);
}

// Round 15
// 245.743 us; speedup vs baseline: 1.3276x; 1.0682x over previous
//
#include <hip/hip_runtime.h>
#include <hip/hip_bf16.h>

#define NB   32
#define CH   64
#define LL   2048
#define OUTC 128

typedef float  f32x4  __attribute__((ext_vector_type(4)));
typedef short  s16x8  __attribute__((ext_vector_type(8)));
typedef short  s16x4  __attribute__((ext_vector_type(4)));
typedef unsigned short u16;

__device__ __forceinline__ u16 f2bf(float f) {
  unsigned int u = __builtin_bit_cast(unsigned int, f);
  u += 0x7FFFu + ((u >> 16) & 1u);           // RNE (scalar epilogue use)
  return (u16)(u >> 16);
}

__device__ __forceinline__ s16x8 pack8c(const float* v) {
  s16x8 r;
#pragma unroll
  for (int j = 0; j < 8; j += 2) {
    __hip_bfloat162 h = __float22bfloat162_rn(make_float2(v[j], v[j + 1]));
    short2 s;
    __builtin_memcpy(&s, &h, sizeof(s));
    r[j] = s.x; r[j + 1] = s.y;
  }
  return r;
}

__device__ __forceinline__ s16x4 pack4c(const f32x4& v) {
  s16x4 r;
  __hip_bfloat162 h0 = __float22bfloat162_rn(make_float2(v[0], v[1]));
  __hip_bfloat162 h1 = __float22bfloat162_rn(make_float2(v[2], v[3]));
  short2 s0, s1;
  __builtin_memcpy(&s0, &h0, sizeof(s0));
  __builtin_memcpy(&s1, &h1, sizeof(s1));
  r[0] = s0.x; r[1] = s0.y; r[2] = s1.x; r[3] = s1.y;
  return r;
}

// ---------------------------------------------------------------------------
// K0: x (fp32->bf16), W (fp32->bf16)
// ---------------------------------------------------------------------------
#define NX (NB * CH * LL)          // 4,194,304
#define NW (OUTC * 3 * CH)         // 24,576
__global__ __launch_bounds__(256)
void cvt_inputs(const float* __restrict__ x, const float* __restrict__ W,
                u16* __restrict__ xb, u16* __restrict__ Wb)
{
  const size_t t8 = ((size_t)blockIdx.x * 256 + threadIdx.x) * 8;
  if (t8 < NX) {
    float v[8];
    *(f32x4*)(v)     = *(const f32x4*)(x + t8);
    *(f32x4*)(v + 4) = *(const f32x4*)(x + t8 + 4);
    *(s16x8*)(xb + t8) = pack8c(v);
  } else if (t8 - NX < NW) {
    const size_t w8 = t8 - NX;
    float v[8];
    *(f32x4*)(v)     = *(const f32x4*)(W + w8);
    *(f32x4*)(v + 4) = *(const f32x4*)(W + w8 + 4);
    *(s16x8*)(Wb + w8) = pack8c(v);
  }
}

// ---------------------------------------------------------------------------
// K1: y1[n] = xb[n] * m[n]  (+ writes mP bf16 B-fragments for K2)
// 256-col tiles, 1 KB-contiguous gload_lds rows, grid 256, 96 KiB LDS
// triple-buffer, distance-2, counted vmcnt + raw s_barrier.
// (byte-identical to the 262.5 us round-14 kernel)
// ---------------------------------------------------------------------------
__global__ __launch_bounds__(256)
void prop1_pack(const u16* __restrict__ xb, const float* __restrict__ m,
                u16* __restrict__ y1, u16* __restrict__ mP)
{
  __shared__ float smem[3][32 * 256];   // 96 KiB triple-buffered 32x256 fp32

  const int n    = blockIdx.x >> 3;
  const int lt   = blockIdx.x & 7;
  const int tid  = threadIdx.x;
  const int wave = tid >> 6;
  const int lane = tid & 63;
  const int l15  = lane & 15;
  const int g4   = lane >> 4;
  const int colb = lt * 256 + wave * 64;

  const float* mn   = m + (size_t)n * LL * LL + lt * 256;
  const float* gsrc = mn + (size_t)wave * LL + lane * 4;
  const u16*   ap   = xb + (size_t)n * CH * LL + (size_t)l15 * LL + g4 * 8;
  u16* q0 = mP + (((size_t)n * 64 * LL + colb + l15) * 4 + g4) * 8; // + kb*65536, h*512
  u16* o  = y1 + (size_t)n * CH * LL + colb + l15;

  f32x4 acc[4][4];
#pragma unroll
  for (int f = 0; f < 4; ++f)
#pragma unroll
    for (int h = 0; h < 4; ++h)
#pragma unroll
      for (int r = 0; r < 4; ++r) acc[f][h][r] = 0.f;

  s16x8 aP[4], aQ[4];

#define ALOAD(R, KB)                                                          \
  { const u16* _ap = ap + (KB) * 32;                                          \
    _Pragma("unroll") for (int f = 0; f < 4; ++f)                             \
      R[f] = *(const s16x8*)(_ap + (size_t)(f * 16) * LL); }

#define GLOAD(BI, KB)                                                         \
  { float* _sb = smem[BI];                                                    \
    _Pragma("unroll") for (int i = 0; i < 8; ++i) {                           \
      const float* _g = gsrc + (size_t)((KB) * 32 + i * 4) * LL;              \
      __builtin_amdgcn_global_load_lds(                                       \
        (const __attribute__((address_space(1))) void*)_g,                    \
        (__attribute__((address_space(3))) void*)(_sb + i * 1024 + wave * 256),\
        16, 0, 0); } }

  ALOAD(aP, 0)
  __builtin_amdgcn_sched_barrier(0);
  GLOAD(0, 0) GLOAD(1, 1)
  __builtin_amdgcn_sched_barrier(0);
  asm volatile("s_waitcnt vmcnt(8)" ::: "memory");
  __builtin_amdgcn_s_barrier();
  __builtin_amdgcn_sched_barrier(0);

#define K1_STEP(KB, CUR, NXT, GI, BI, VN, DOA, DOG, DOBAR)                    \
  {                                                                           \
    if (DOA) {                                                                \
      ALOAD(NXT, (KB) + 1)                                                    \
      __builtin_amdgcn_sched_barrier(0);                                      \
    }                                                                         \
    if (DOG) {                                                                \
      GLOAD(GI, (KB) + 2)                                                     \
      __builtin_amdgcn_sched_barrier(0);                                      \
    }                                                                         \
    const float* _t = smem[BI] + wave * 64 + l15;                             \
    s16x8 _b[4];                                                              \
    _Pragma("unroll") for (int h = 0; h < 4; ++h) {                           \
      float _bv[8];                                                           \
      _Pragma("unroll") for (int j = 0; j < 8; ++j)                           \
        _bv[j] = _t[(g4 * 8 + j) * 256 + h * 16];                             \
      _b[h] = pack8c(_bv);                                                    \
    }                                                                         \
    u16* _q = q0 + (size_t)(KB) * 65536;                                      \
    _Pragma("unroll") for (int h = 0; h < 4; ++h)                             \
      *(s16x8*)(_q + h * 512) = _b[h];                                        \
    _Pragma("unroll") for (int f = 0; f < 4; ++f)                             \
      _Pragma("unroll") for (int h = 0; h < 4; ++h)                           \
        acc[f][h] = __builtin_amdgcn_mfma_f32_16x16x32_bf16(CUR[f], _b[h], acc[f][h], 0, 0, 0); \
    if (DOBAR) {                                                              \
      __builtin_amdgcn_sched_barrier(0);                                      \
      asm volatile("s_waitcnt vmcnt(" VN ")" ::: "memory");                   \
      __builtin_amdgcn_s_barrier();                                           \
      __builtin_amdgcn_sched_barrier(0);                                      \
    }                                                                         \
  }

  K1_STEP(0, aP, aQ, 2, 0, "16", 1, 1, 1)
#pragma unroll 1
  for (int kb = 1; kb <= 55; kb += 6) {
    K1_STEP(kb,     aQ, aP, 0, 1, "20", 1, 1, 1)
    K1_STEP(kb + 1, aP, aQ, 1, 2, "20", 1, 1, 1)
    K1_STEP(kb + 2, aQ, aP, 2, 0, "20", 1, 1, 1)
    K1_STEP(kb + 3, aP, aQ, 0, 1, "20", 1, 1, 1)
    K1_STEP(kb + 4, aQ, aP, 1, 2, "20", 1, 1, 1)
    K1_STEP(kb + 5, aP, aQ, 2, 0, "20", 1, 1, 1)
  }
  K1_STEP(61, aQ, aP, 0, 1, "20", 1, 1, 1)
  K1_STEP(62, aP, aQ, 0, 2, "12", 1, 0, 1)
  K1_STEP(63, aQ, aP, 0, 0, "0",  0, 0, 0)

#pragma unroll
  for (int f = 0; f < 4; ++f)
#pragma unroll
    for (int h = 0; h < 4; ++h)
#pragma unroll
      for (int r = 0; r < 4; ++r) {
        const int row = f * 16 + g4 * 4 + r;
        o[(size_t)row * LL + h * 16] = f2bf(acc[f][h][r]);
      }
}

// ---------------------------------------------------------------------------
// K2: y2 = y1 * m (from mP) FUSED with projection.
// REBUILT mP path: each (kb, 128-col) tile is one contiguous 8 KB block ->
// gload_lds (2 x 1 KB per wave), triple-buffered, distance-2, uniform
// counted vmcnt(6) gate (doubles as the A-register wait) + raw s_barrier.
// LDS B-read is 64-lane contiguous 1 KB ds_read_b128 (conflict-free).
// ---------------------------------------------------------------------------
__global__ __launch_bounds__(256, 3)
void prop2_proj(const u16* __restrict__ y1, const u16* __restrict__ mP,
                const u16* __restrict__ xb, const u16* __restrict__ Wb,
                const float* __restrict__ bias, float* __restrict__ out)
{
  __shared__ u16 smem2[3][4096];   // 3 x 8 KiB mP tile (128 col x 4 g4 x 8 bf16)
  __shared__ u16 yT[128 * 72];     // col-major y2 tile, 18 KiB

  const int n    = blockIdx.x >> 4;
  const int lt   = blockIdx.x & 15;
  const int tid  = threadIdx.x;
  const int wave = tid >> 6;
  const int lane = tid & 63;
  const int l15  = lane & 15;
  const int g4   = lane >> 4;
  const int colb = lt * 128 + wave * 32;

  // tile base (kb=0): ((n*64)*2048 + lt*128)*32 u16; kb stride 65536 u16
  const u16* gsrc2 = mP + ((size_t)n * 64 * LL + lt * 128) * 32
                        + wave * 1024 + lane * 8;
  const u16* ap = y1 + (size_t)n * CH * LL + (size_t)l15 * LL + g4 * 8;

  f32x4 acc[4][2];
#pragma unroll
  for (int f = 0; f < 4; ++f)
#pragma unroll
    for (int h = 0; h < 2; ++h)
#pragma unroll
      for (int r = 0; r < 4; ++r) acc[f][h][r] = 0.f;

  s16x8 aP2[4], aQ2[4];

#define ALOAD2(R, KB)                                                         \
  { const u16* _ap = ap + (KB) * 32;                                          \
    _Pragma("unroll") for (int f = 0; f < 4; ++f)                             \
      R[f] = *(const s16x8*)(_ap + (size_t)(f * 16) * LL); }

#define GLOAD2(BI, KB)                                                        \
  { u16* _sb = smem2[BI];                                                     \
    _Pragma("unroll") for (int i = 0; i < 2; ++i) {                           \
      const u16* _g = gsrc2 + (size_t)(KB) * 65536 + i * 512;                 \
      __builtin_amdgcn_global_load_lds(                                       \
        (const __attribute__((address_space(1))) void*)_g,                    \
        (__attribute__((address_space(3))) void*)(_sb + wave * 1024 + i * 512),\
        16, 0, 0); } }

  // prologue: A0 (oldest), G0, G1; gate G0 (only G1:2 newer)
  ALOAD2(aP2, 0)
  __builtin_amdgcn_sched_barrier(0);
  GLOAD2(0, 0) GLOAD2(1, 1)
  __builtin_amdgcn_sched_barrier(0);
  asm volatile("s_waitcnt vmcnt(2)" ::: "memory");
  __builtin_amdgcn_s_barrier();
  __builtin_amdgcn_sched_barrier(0);

  // step KB: issue A(KB+1):4, G(KB+2):2; gate vmcnt(VN) retires G(KB)+A(KB);
  // ds_read B from buf BI; 8 MFMA; end barrier gates next overwrite.
#define K2_STEP(KB, CUR, NXT, GI, BI, VN, DOA, DOG, DOBAR)                    \
  {                                                                           \
    if (DOA) {                                                                \
      ALOAD2(NXT, (KB) + 1)                                                   \
      __builtin_amdgcn_sched_barrier(0);                                      \
    }                                                                         \
    if (DOG) {                                                                \
      GLOAD2(GI, (KB) + 2)                                                    \
      __builtin_amdgcn_sched_barrier(0);                                      \
    }                                                                         \
    asm volatile("s_waitcnt vmcnt(" VN ")" ::: "memory");                     \
    __builtin_amdgcn_sched_barrier(0);                                        \
    const u16* _t = smem2[BI] + wave * 1024 + l15 * 32 + g4 * 8;              \
    s16x8 _b0 = *(const s16x8*)(_t);                                          \
    s16x8 _b1 = *(const s16x8*)(_t + 512);                                    \
    _Pragma("unroll") for (int f = 0; f < 4; ++f) {                           \
      acc[f][0] = __builtin_amdgcn_mfma_f32_16x16x32_bf16(CUR[f], _b0, acc[f][0], 0, 0, 0); \
      acc[f][1] = __builtin_amdgcn_mfma_f32_16x16x32_bf16(CUR[f], _b1, acc[f][1], 0, 0, 0); \
    }                                                                         \
    if (DOBAR) {                                                              \
      __builtin_amdgcn_sched_barrier(0);                                      \
      __builtin_amdgcn_s_barrier();                                           \
      __builtin_amdgcn_sched_barrier(0);                                      \
    }                                                                         \
  }

  K2_STEP(0, aP2, aQ2, 2, 0, "6", 1, 1, 1)
#pragma unroll 1
  for (int kb = 1; kb <= 55; kb += 6) {
    K2_STEP(kb,     aQ2, aP2, 0, 1, "6", 1, 1, 1)
    K2_STEP(kb + 1, aP2, aQ2, 1, 2, "6", 1, 1, 1)
    K2_STEP(kb + 2, aQ2, aP2, 2, 0, "6", 1, 1, 1)
    K2_STEP(kb + 3, aP2, aQ2, 0, 1, "6", 1, 1, 1)
    K2_STEP(kb + 4, aQ2, aP2, 1, 2, "6", 1, 1, 1)
    K2_STEP(kb + 5, aP2, aQ2, 2, 0, "6", 1, 1, 1)
  }
  K2_STEP(61, aQ2, aP2, 0, 1, "6", 1, 1, 1)
  K2_STEP(62, aP2, aQ2, 0, 2, "6", 1, 0, 1)   // issues A63 only
  K2_STEP(63, aQ2, aP2, 0, 0, "0", 0, 0, 0)

  // ---- epilogue: y2 (acc) -> LDS col-major bf16 ----
#pragma unroll
  for (int f = 0; f < 4; ++f)
#pragma unroll
    for (int h = 0; h < 2; ++h) {
      const int c = wave * 32 + l15 + 16 * h;
      *(s16x4*)(&yT[c * 72 + f * 16 + g4 * 4]) = pack4c(acc[f][h]);
    }
  __syncthreads();

  // ---- projection: out = Wb(128x192) * [xb;y1;y2] + b ----
  f32x4 acc2[8][2];
#pragma unroll
  for (int f = 0; f < 8; ++f)
#pragma unroll
    for (int h = 0; h < 2; ++h)
#pragma unroll
      for (int r = 0; r < 4; ++r) acc2[f][h][r] = 0.f;

  const size_t cb = (size_t)n * CH * LL + colb + l15;
  const u16* xp  = xb + cb + (size_t)(g4 * 8) * LL;
  const u16* y1p = y1 + cb + (size_t)(g4 * 8) * LL;
  const u16* wq  = Wb + (size_t)l15 * 192 + g4 * 8;

#pragma unroll
  for (int kc = 0; kc < 6; ++kc) {
    const int k0 = kc * 32;
    s16x8 b0, b1;
    if (kc < 4) {
      const u16* src = (kc < 2) ? (xp + (size_t)k0 * LL)
                                : (y1p + (size_t)(k0 - 64) * LL);
#pragma unroll
      for (int j = 0; j < 8; ++j) {
        b0[j] = (short)src[(size_t)j * LL];
        b1[j] = (short)src[(size_t)j * LL + 16];
      }
    } else {
      const int rb = (kc - 4) * 32 + g4 * 8;
      b0 = *(const s16x8*)(&yT[(wave * 32 + l15) * 72 + rb]);
      b1 = *(const s16x8*)(&yT[(wave * 32 + l15 + 16) * 72 + rb]);
    }
#pragma unroll
    for (int f = 0; f < 8; ++f) {
      s16x8 af = *(const s16x8*)(wq + (size_t)(f * 16) * 192 + k0);
      acc2[f][0] = __builtin_amdgcn_mfma_f32_16x16x32_bf16(af, b0, acc2[f][0], 0, 0, 0);
      acc2[f][1] = __builtin_amdgcn_mfma_f32_16x16x32_bf16(af, b1, acc2[f][1], 0, 0, 0);
    }
  }

  float* op = out + (size_t)n * OUTC * LL + colb + l15;
#pragma unroll
  for (int f = 0; f < 8; ++f)
#pragma unroll
    for (int r = 0; r < 4; ++r) {
      const int row = f * 16 + g4 * 4 + r;
      op[(size_t)row * LL]      = acc2[f][0][r] + bias[row];
      op[(size_t)row * LL + 16] = acc2[f][1][r] + bias[row];
    }
}

extern "C" void kernel_launch(void* const* d_in, const int* in_sizes, int n_in,
                              void* d_out, int out_size, void* d_ws, size_t ws_size,
                              hipStream_t stream)
{
  const float* x = (const float*)d_in[0];
  const float* m = (const float*)d_in[1];
  const float* W = (const float*)d_in[2];
  const float* b = (const float*)d_in[3];
  float* out = (float*)d_out;

  // workspace layout (u16 elems): y1 | xb | Wb | mP
  u16* y1 = (u16*)d_ws;                          //  8 MiB
  u16* xb = y1 + (size_t)NB * CH * LL;           //  8 MiB
  u16* Wb = xb + (size_t)NB * CH * LL;           // 48 KiB
  u16* mP = (u16*)((char*)d_ws + (25u << 20));   // 256 MiB, 1 MiB-aligned

  cvt_inputs<<<dim3(2060), dim3(256), 0, stream>>>(x, W, xb, Wb);
  prop1_pack<<<dim3(NB * 8), dim3(256), 0, stream>>>(xb, m, y1, mP);
  prop2_proj<<<dim3(NB * 16), dim3(256), 0, stream>>>(y1, mP, xb, Wb, b, out);
}

// Round 16
// 229.018 us; speedup vs baseline: 1.4245x; 1.0730x over previous
//
#include <hip/hip_runtime.h>
#include <hip/hip_bf16.h>

#define NB   32
#define CH   64
#define LL   2048
#define OUTC 128

typedef float  f32x4  __attribute__((ext_vector_type(4)));
typedef short  s16x8  __attribute__((ext_vector_type(8)));
typedef short  s16x4  __attribute__((ext_vector_type(4)));
typedef unsigned short u16;

__device__ __forceinline__ u16 f2bf(float f) {
  unsigned int u = __builtin_bit_cast(unsigned int, f);
  u += 0x7FFFu + ((u >> 16) & 1u);           // RNE (scalar epilogue use)
  return (u16)(u >> 16);
}

__device__ __forceinline__ s16x8 pack8c(const float* v) {
  s16x8 r;
#pragma unroll
  for (int j = 0; j < 8; j += 2) {
    __hip_bfloat162 h = __float22bfloat162_rn(make_float2(v[j], v[j + 1]));
    short2 s;
    __builtin_memcpy(&s, &h, sizeof(s));
    r[j] = s.x; r[j + 1] = s.y;
  }
  return r;
}

__device__ __forceinline__ s16x4 pack4c(const f32x4& v) {
  s16x4 r;
  __hip_bfloat162 h0 = __float22bfloat162_rn(make_float2(v[0], v[1]));
  __hip_bfloat162 h1 = __float22bfloat162_rn(make_float2(v[2], v[3]));
  short2 s0, s1;
  __builtin_memcpy(&s0, &h0, sizeof(s0));
  __builtin_memcpy(&s1, &h1, sizeof(s1));
  r[0] = s0.x; r[1] = s0.y; r[2] = s1.x; r[3] = s1.y;
  return r;
}

// ---------------------------------------------------------------------------
// K0: x (fp32->bf16), W (fp32->bf16)
// ---------------------------------------------------------------------------
#define NX (NB * CH * LL)          // 4,194,304
#define NW (OUTC * 3 * CH)         // 24,576
__global__ __launch_bounds__(256)
void cvt_inputs(const float* __restrict__ x, const float* __restrict__ W,
                u16* __restrict__ xb, u16* __restrict__ Wb)
{
  const size_t t8 = ((size_t)blockIdx.x * 256 + threadIdx.x) * 8;
  if (t8 < NX) {
    float v[8];
    *(f32x4*)(v)     = *(const f32x4*)(x + t8);
    *(f32x4*)(v + 4) = *(const f32x4*)(x + t8 + 4);
    *(s16x8*)(xb + t8) = pack8c(v);
  } else if (t8 - NX < NW) {
    const size_t w8 = t8 - NX;
    float v[8];
    *(f32x4*)(v)     = *(const f32x4*)(W + w8);
    *(f32x4*)(v + 4) = *(const f32x4*)(W + w8 + 4);
    *(s16x8*)(Wb + w8) = pack8c(v);
  }
}

// ---------------------------------------------------------------------------
// K1: y1[n] = xb[n] * m[n].  PURE-READ K-loop: the mP pack/stores are GONE
// (mixed R/W stream hypothesis). 256-col tiles, 1 KB gload_lds rows, grid
// 256, 96 KiB triple-buffer, distance-2, counted vmcnt + raw s_barrier.
// Per-step issue [A:4][G:8]; gates: prologue 8, steady 12, tail 4.
// ---------------------------------------------------------------------------
__global__ __launch_bounds__(256)
void prop1(const u16* __restrict__ xb, const float* __restrict__ m,
           u16* __restrict__ y1)
{
  __shared__ float smem[3][32 * 256];

  const int n    = blockIdx.x >> 3;
  const int lt   = blockIdx.x & 7;
  const int tid  = threadIdx.x;
  const int wave = tid >> 6;
  const int lane = tid & 63;
  const int l15  = lane & 15;
  const int g4   = lane >> 4;
  const int colb = lt * 256 + wave * 64;

  const float* mn   = m + (size_t)n * LL * LL + lt * 256;
  const float* gsrc = mn + (size_t)wave * LL + lane * 4;
  const u16*   ap   = xb + (size_t)n * CH * LL + (size_t)l15 * LL + g4 * 8;
  u16* o = y1 + (size_t)n * CH * LL + colb + l15;

  f32x4 acc[4][4];
#pragma unroll
  for (int f = 0; f < 4; ++f)
#pragma unroll
    for (int h = 0; h < 4; ++h)
#pragma unroll
      for (int r = 0; r < 4; ++r) acc[f][h][r] = 0.f;

  s16x8 aP[4], aQ[4];

#define ALOAD(R, KB)                                                          \
  { const u16* _ap = ap + (KB) * 32;                                          \
    _Pragma("unroll") for (int f = 0; f < 4; ++f)                             \
      R[f] = *(const s16x8*)(_ap + (size_t)(f * 16) * LL); }

#define GLOAD(BI, KB)                                                         \
  { float* _sb = smem[BI];                                                    \
    _Pragma("unroll") for (int i = 0; i < 8; ++i) {                           \
      const float* _g = gsrc + (size_t)((KB) * 32 + i * 4) * LL;              \
      __builtin_amdgcn_global_load_lds(                                       \
        (const __attribute__((address_space(1))) void*)_g,                    \
        (__attribute__((address_space(3))) void*)(_sb + i * 1024 + wave * 256),\
        16, 0, 0); } }

  ALOAD(aP, 0)
  __builtin_amdgcn_sched_barrier(0);
  GLOAD(0, 0) GLOAD(1, 1)
  __builtin_amdgcn_sched_barrier(0);
  asm volatile("s_waitcnt vmcnt(8)" ::: "memory");   // retire A0+G0, leave G1
  __builtin_amdgcn_s_barrier();
  __builtin_amdgcn_sched_barrier(0);

#define K1_STEP(KB, CUR, NXT, GI, BI, VN, DOA, DOG, DOBAR)                    \
  {                                                                           \
    if (DOA) {                                                                \
      ALOAD(NXT, (KB) + 1)                                                    \
      __builtin_amdgcn_sched_barrier(0);                                      \
    }                                                                         \
    if (DOG) {                                                                \
      GLOAD(GI, (KB) + 2)                                                     \
      __builtin_amdgcn_sched_barrier(0);                                      \
    }                                                                         \
    const float* _t = smem[BI] + wave * 64 + l15;                             \
    s16x8 _b[4];                                                              \
    _Pragma("unroll") for (int h = 0; h < 4; ++h) {                           \
      float _bv[8];                                                           \
      _Pragma("unroll") for (int j = 0; j < 8; ++j)                           \
        _bv[j] = _t[(g4 * 8 + j) * 256 + h * 16];                             \
      _b[h] = pack8c(_bv);                                                    \
    }                                                                         \
    _Pragma("unroll") for (int f = 0; f < 4; ++f)                             \
      _Pragma("unroll") for (int h = 0; h < 4; ++h)                           \
        acc[f][h] = __builtin_amdgcn_mfma_f32_16x16x32_bf16(CUR[f], _b[h], acc[f][h], 0, 0, 0); \
    if (DOBAR) {                                                              \
      __builtin_amdgcn_sched_barrier(0);                                      \
      asm volatile("s_waitcnt vmcnt(" VN ")" ::: "memory");                   \
      __builtin_amdgcn_s_barrier();                                           \
      __builtin_amdgcn_sched_barrier(0);                                      \
    }                                                                         \
  }

  K1_STEP(0, aP, aQ, 2, 0, "12", 1, 1, 1)
#pragma unroll 1
  for (int kb = 1; kb <= 55; kb += 6) {
    K1_STEP(kb,     aQ, aP, 0, 1, "12", 1, 1, 1)
    K1_STEP(kb + 1, aP, aQ, 1, 2, "12", 1, 1, 1)
    K1_STEP(kb + 2, aQ, aP, 2, 0, "12", 1, 1, 1)
    K1_STEP(kb + 3, aP, aQ, 0, 1, "12", 1, 1, 1)
    K1_STEP(kb + 4, aQ, aP, 1, 2, "12", 1, 1, 1)
    K1_STEP(kb + 5, aP, aQ, 2, 0, "12", 1, 1, 1)
  }
  K1_STEP(61, aQ, aP, 0, 1, "12", 1, 1, 1)
  K1_STEP(62, aP, aQ, 0, 2, "4",  1, 0, 1)
  K1_STEP(63, aQ, aP, 0, 0, "0",  0, 0, 0)

#pragma unroll
  for (int f = 0; f < 4; ++f)
#pragma unroll
    for (int h = 0; h < 4; ++h)
#pragma unroll
      for (int r = 0; r < 4; ++r) {
        const int row = f * 16 + g4 * 4 + r;
        o[(size_t)row * LL + h * 16] = f2bf(acc[f][h][r]);
      }
}

// ---------------------------------------------------------------------------
// K2: y2 = y1 * m, re-staging m fp32 with the SAME structure as K1 (pure-read
// K-loop), then fused projection out = Wb*[xb;y1;y2] + b.  yT is overlaid on
// the staging LDS after the K-loop.
// ---------------------------------------------------------------------------
__global__ __launch_bounds__(256)
void prop2m_proj(const u16* __restrict__ y1, const float* __restrict__ m,
                 const u16* __restrict__ xb, const u16* __restrict__ Wb,
                 const float* __restrict__ bias, float* __restrict__ out)
{
  __shared__ float smem[3][32 * 256];   // staging; later overlaid by yT (36 KiB)

  const int n    = blockIdx.x >> 3;
  const int lt   = blockIdx.x & 7;
  const int tid  = threadIdx.x;
  const int wave = tid >> 6;
  const int lane = tid & 63;
  const int l15  = lane & 15;
  const int g4   = lane >> 4;
  const int colb = lt * 256 + wave * 64;

  const float* mn   = m + (size_t)n * LL * LL + lt * 256;
  const float* gsrc = mn + (size_t)wave * LL + lane * 4;
  const u16*   ap   = y1 + (size_t)n * CH * LL + (size_t)l15 * LL + g4 * 8;

  f32x4 acc[4][4];
#pragma unroll
  for (int f = 0; f < 4; ++f)
#pragma unroll
    for (int h = 0; h < 4; ++h)
#pragma unroll
      for (int r = 0; r < 4; ++r) acc[f][h][r] = 0.f;

  s16x8 aP[4], aQ[4];

  ALOAD(aP, 0)
  __builtin_amdgcn_sched_barrier(0);
  GLOAD(0, 0) GLOAD(1, 1)
  __builtin_amdgcn_sched_barrier(0);
  asm volatile("s_waitcnt vmcnt(8)" ::: "memory");
  __builtin_amdgcn_s_barrier();
  __builtin_amdgcn_sched_barrier(0);

  K1_STEP(0, aP, aQ, 2, 0, "12", 1, 1, 1)
#pragma unroll 1
  for (int kb = 1; kb <= 55; kb += 6) {
    K1_STEP(kb,     aQ, aP, 0, 1, "12", 1, 1, 1)
    K1_STEP(kb + 1, aP, aQ, 1, 2, "12", 1, 1, 1)
    K1_STEP(kb + 2, aQ, aP, 2, 0, "12", 1, 1, 1)
    K1_STEP(kb + 3, aP, aQ, 0, 1, "12", 1, 1, 1)
    K1_STEP(kb + 4, aQ, aP, 1, 2, "12", 1, 1, 1)
    K1_STEP(kb + 5, aP, aQ, 2, 0, "12", 1, 1, 1)
  }
  K1_STEP(61, aQ, aP, 0, 1, "12", 1, 1, 1)
  K1_STEP(62, aP, aQ, 0, 2, "4",  1, 0, 1)
  K1_STEP(63, aQ, aP, 0, 0, "0",  0, 0, 0)

  // ---- epilogue: y2 (acc) -> yT col-major bf16, overlaid on smem ----
  __syncthreads();                     // all waves done reading stage buffers
  u16* yT = (u16*)&smem[0][0];         // yT[c*72 + r], 256 x 72 u16 = 36 KiB
#pragma unroll
  for (int f = 0; f < 4; ++f)
#pragma unroll
    for (int h = 0; h < 4; ++h) {
      const int c = wave * 64 + h * 16 + l15;
      *(s16x4*)(&yT[c * 72 + f * 16 + g4 * 4]) = pack4c(acc[f][h]);
    }
  __syncthreads();

  // ---- projection: out = Wb(128x192) * [xb;y1;y2] + b ----
  f32x4 acc2[8][4];
#pragma unroll
  for (int f = 0; f < 8; ++f)
#pragma unroll
    for (int h = 0; h < 4; ++h)
#pragma unroll
      for (int r = 0; r < 4; ++r) acc2[f][h][r] = 0.f;

  const size_t cb = (size_t)n * CH * LL + colb + l15;
  const u16* xp  = xb + cb + (size_t)(g4 * 8) * LL;
  const u16* y1p = y1 + cb + (size_t)(g4 * 8) * LL;
  const u16* wq  = Wb + (size_t)l15 * 192 + g4 * 8;

#pragma unroll
  for (int kc = 0; kc < 6; ++kc) {
    const int k0 = kc * 32;
    s16x8 b[4];
    if (kc < 4) {
      const u16* src = (kc < 2) ? (xp + (size_t)k0 * LL)
                                : (y1p + (size_t)(k0 - 64) * LL);
#pragma unroll
      for (int h = 0; h < 4; ++h)
#pragma unroll
        for (int j = 0; j < 8; ++j)
          b[h][j] = (short)src[(size_t)j * LL + h * 16];
    } else {
      const int rb = (kc - 4) * 32 + g4 * 8;
#pragma unroll
      for (int h = 0; h < 4; ++h)
        b[h] = *(const s16x8*)(&yT[(wave * 64 + h * 16 + l15) * 72 + rb]);
    }
#pragma unroll
    for (int f = 0; f < 8; ++f) {
      s16x8 af = *(const s16x8*)(wq + (size_t)(f * 16) * 192 + k0);
#pragma unroll
      for (int h = 0; h < 4; ++h)
        acc2[f][h] = __builtin_amdgcn_mfma_f32_16x16x32_bf16(af, b[h], acc2[f][h], 0, 0, 0);
    }
  }

  float* op = out + (size_t)n * OUTC * LL + colb + l15;
#pragma unroll
  for (int f = 0; f < 8; ++f)
#pragma unroll
    for (int h = 0; h < 4; ++h)
#pragma unroll
      for (int r = 0; r < 4; ++r) {
        const int row = f * 16 + g4 * 4 + r;
        op[(size_t)row * LL + h * 16] = acc2[f][h][r] + bias[row];
      }
}

extern "C" void kernel_launch(void* const* d_in, const int* in_sizes, int n_in,
                              void* d_out, int out_size, void* d_ws, size_t ws_size,
                              hipStream_t stream)
{
  const float* x = (const float*)d_in[0];
  const float* m = (const float*)d_in[1];
  const float* W = (const float*)d_in[2];
  const float* b = (const float*)d_in[3];
  float* out = (float*)d_out;

  // workspace layout (u16 elems): y1 | xb | Wb   (mP eliminated)
  u16* y1 = (u16*)d_ws;                          //  8 MiB
  u16* xb = y1 + (size_t)NB * CH * LL;           //  8 MiB
  u16* Wb = xb + (size_t)NB * CH * LL;           // 48 KiB

  cvt_inputs<<<dim3(2060), dim3(256), 0, stream>>>(x, W, xb, Wb);
  prop1<<<dim3(NB * 8), dim3(256), 0, stream>>>(xb, m, y1);
  prop2m_proj<<<dim3(NB * 8), dim3(256), 0, stream>>>(y1, m, xb, Wb, b, out);
}

// Round 17
// 227.813 us; speedup vs baseline: 1.4321x; 1.0053x over previous
//
#include <hip/hip_runtime.h>
#include <hip/hip_bf16.h>

#define NB   32
#define CH   64
#define LL   2048
#define OUTC 128

typedef float  f32x4  __attribute__((ext_vector_type(4)));
typedef short  s16x8  __attribute__((ext_vector_type(8)));
typedef short  s16x4  __attribute__((ext_vector_type(4)));
typedef unsigned short u16;

__device__ __forceinline__ u16 f2bf(float f) {
  unsigned int u = __builtin_bit_cast(unsigned int, f);
  u += 0x7FFFu + ((u >> 16) & 1u);           // RNE (scalar epilogue use)
  return (u16)(u >> 16);
}

__device__ __forceinline__ s16x8 pack8c(const float* v) {
  s16x8 r;
#pragma unroll
  for (int j = 0; j < 8; j += 2) {
    __hip_bfloat162 h = __float22bfloat162_rn(make_float2(v[j], v[j + 1]));
    short2 s;
    __builtin_memcpy(&s, &h, sizeof(s));
    r[j] = s.x; r[j + 1] = s.y;
  }
  return r;
}

__device__ __forceinline__ s16x4 pack4c(const f32x4& v) {
  s16x4 r;
  __hip_bfloat162 h0 = __float22bfloat162_rn(make_float2(v[0], v[1]));
  __hip_bfloat162 h1 = __float22bfloat162_rn(make_float2(v[2], v[3]));
  short2 s0, s1;
  __builtin_memcpy(&s0, &h0, sizeof(s0));
  __builtin_memcpy(&s1, &h1, sizeof(s1));
  r[0] = s0.x; r[1] = s0.y; r[2] = s1.x; r[3] = s1.y;
  return r;
}

// ---------------------------------------------------------------------------
// K0: x (fp32->bf16), W (fp32->bf16)
// ---------------------------------------------------------------------------
#define NX (NB * CH * LL)          // 4,194,304
#define NW (OUTC * 3 * CH)         // 24,576
__global__ __launch_bounds__(256)
void cvt_inputs(const float* __restrict__ x, const float* __restrict__ W,
                u16* __restrict__ xb, u16* __restrict__ Wb)
{
  const size_t t8 = ((size_t)blockIdx.x * 256 + threadIdx.x) * 8;
  if (t8 < NX) {
    float v[8];
    *(f32x4*)(v)     = *(const f32x4*)(x + t8);
    *(f32x4*)(v + 4) = *(const f32x4*)(x + t8 + 4);
    *(s16x8*)(xb + t8) = pack8c(v);
  } else if (t8 - NX < NW) {
    const size_t w8 = t8 - NX;
    float v[8];
    *(f32x4*)(v)     = *(const f32x4*)(W + w8);
    *(f32x4*)(v + 4) = *(const f32x4*)(W + w8 + 4);
    *(s16x8*)(Wb + w8) = pack8c(v);
  }
}

// ---------------------------------------------------------------------------
// K1: y1[n] = xb[n] * m[n].  Pure-read K-loop, 256-col tiles, 1 KB gload_lds
// rows, grid 256.  DEPTH-3: QUAD-buffered (128 KiB LDS, still 1 block/CU),
// two spare tiles in flight across every barrier (jitter absorption).
// Per-step issue [A:4][G:8]; gates: prologue 16, steady 20, tail 12/4.
// ---------------------------------------------------------------------------
__global__ __launch_bounds__(256)
void prop1(const u16* __restrict__ xb, const float* __restrict__ m,
           u16* __restrict__ y1)
{
  __shared__ float smem[4][32 * 256];   // 128 KiB quad-buffered 32x256 fp32

  const int n    = blockIdx.x >> 3;
  const int lt   = blockIdx.x & 7;
  const int tid  = threadIdx.x;
  const int wave = tid >> 6;
  const int lane = tid & 63;
  const int l15  = lane & 15;
  const int g4   = lane >> 4;
  const int colb = lt * 256 + wave * 64;

  const float* mn   = m + (size_t)n * LL * LL + lt * 256;
  const float* gsrc = mn + (size_t)wave * LL + lane * 4;
  const u16*   ap   = xb + (size_t)n * CH * LL + (size_t)l15 * LL + g4 * 8;
  u16* o = y1 + (size_t)n * CH * LL + colb + l15;

  f32x4 acc[4][4];
#pragma unroll
  for (int f = 0; f < 4; ++f)
#pragma unroll
    for (int h = 0; h < 4; ++h)
#pragma unroll
      for (int r = 0; r < 4; ++r) acc[f][h][r] = 0.f;

  s16x8 aP[4], aQ[4];

#define ALOAD(R, KB)                                                          \
  { const u16* _ap = ap + (KB) * 32;                                          \
    _Pragma("unroll") for (int f = 0; f < 4; ++f)                             \
      R[f] = *(const s16x8*)(_ap + (size_t)(f * 16) * LL); }

#define GLOAD(BI, KB)                                                         \
  { float* _sb = smem[BI];                                                    \
    _Pragma("unroll") for (int i = 0; i < 8; ++i) {                           \
      const float* _g = gsrc + (size_t)((KB) * 32 + i * 4) * LL;              \
      __builtin_amdgcn_global_load_lds(                                       \
        (const __attribute__((address_space(1))) void*)_g,                    \
        (__attribute__((address_space(3))) void*)(_sb + i * 1024 + wave * 256),\
        16, 0, 0); } }

  // prologue: A0 (oldest), tiles 0,1,2; gate tile 0 (G1+G2 = 16 newer)
  ALOAD(aP, 0)
  __builtin_amdgcn_sched_barrier(0);
  GLOAD(0, 0) GLOAD(1, 1) GLOAD(2, 2)
  __builtin_amdgcn_sched_barrier(0);
  asm volatile("s_waitcnt vmcnt(16)" ::: "memory");
  __builtin_amdgcn_s_barrier();
  __builtin_amdgcn_sched_barrier(0);

  // step KB: issue A(KB+1), G(KB+3)->buf GI; compute tile KB from buf BI;
  // end gate retires G(KB+1): steady newer = G(KB+2):8 + A(KB+1):4 + G(KB+3):8 = 20.
#define K1_STEP(KB, CUR, NXT, GI, BI, VN, DOA, DOG, DOBAR)                    \
  {                                                                           \
    if (DOA) {                                                                \
      ALOAD(NXT, (KB) + 1)                                                    \
      __builtin_amdgcn_sched_barrier(0);                                      \
    }                                                                         \
    if (DOG) {                                                                \
      GLOAD(GI, (KB) + 3)                                                     \
      __builtin_amdgcn_sched_barrier(0);                                      \
    }                                                                         \
    const float* _t = smem[BI] + wave * 64 + l15;                             \
    s16x8 _b[4];                                                              \
    _Pragma("unroll") for (int h = 0; h < 4; ++h) {                           \
      float _bv[8];                                                           \
      _Pragma("unroll") for (int j = 0; j < 8; ++j)                           \
        _bv[j] = _t[(g4 * 8 + j) * 256 + h * 16];                             \
      _b[h] = pack8c(_bv);                                                    \
    }                                                                         \
    _Pragma("unroll") for (int f = 0; f < 4; ++f)                             \
      _Pragma("unroll") for (int h = 0; h < 4; ++h)                           \
        acc[f][h] = __builtin_amdgcn_mfma_f32_16x16x32_bf16(CUR[f], _b[h], acc[f][h], 0, 0, 0); \
    if (DOBAR) {                                                              \
      __builtin_amdgcn_sched_barrier(0);                                      \
      asm volatile("s_waitcnt vmcnt(" VN ")" ::: "memory");                   \
      __builtin_amdgcn_s_barrier();                                           \
      __builtin_amdgcn_sched_barrier(0);                                      \
    }                                                                         \
  }

  K1_STEP(0, aP, aQ, 3, 0, "20", 1, 1, 1)
#pragma unroll 1
  for (int kb = 1; kb <= 57; kb += 4) {   // steps 1..60 (G issued while kb<=60)
    K1_STEP(kb,     aQ, aP, 0, 1, "20", 1, 1, 1)
    K1_STEP(kb + 1, aP, aQ, 1, 2, "20", 1, 1, 1)
    K1_STEP(kb + 2, aQ, aP, 2, 3, "20", 1, 1, 1)
    K1_STEP(kb + 3, aP, aQ, 3, 0, "20", 1, 1, 1)
  }
  K1_STEP(61, aQ, aP, 0, 1, "12", 1, 0, 1)   // A62; gate G62: G63+A62 = 12
  K1_STEP(62, aP, aQ, 0, 2, "4",  1, 0, 1)   // A63; gate G63: A63 = 4
  K1_STEP(63, aQ, aP, 0, 3, "0",  0, 0, 0)

#pragma unroll
  for (int f = 0; f < 4; ++f)
#pragma unroll
    for (int h = 0; h < 4; ++h)
#pragma unroll
      for (int r = 0; r < 4; ++r) {
        const int row = f * 16 + g4 * 4 + r;
        o[(size_t)row * LL + h * 16] = f2bf(acc[f][h][r]);
      }
}

// ---------------------------------------------------------------------------
// K2: y2 = y1 * m (same depth-3 structure), then fused projection
// out = Wb*[xb;y1;y2] + b.  yT overlaid on staging LDS after the K-loop.
// ---------------------------------------------------------------------------
__global__ __launch_bounds__(256)
void prop2m_proj(const u16* __restrict__ y1, const float* __restrict__ m,
                 const u16* __restrict__ xb, const u16* __restrict__ Wb,
                 const float* __restrict__ bias, float* __restrict__ out)
{
  __shared__ float smem[4][32 * 256];   // 128 KiB; later overlaid by yT (36 KiB)

  const int n    = blockIdx.x >> 3;
  const int lt   = blockIdx.x & 7;
  const int tid  = threadIdx.x;
  const int wave = tid >> 6;
  const int lane = tid & 63;
  const int l15  = lane & 15;
  const int g4   = lane >> 4;
  const int colb = lt * 256 + wave * 64;

  const float* mn   = m + (size_t)n * LL * LL + lt * 256;
  const float* gsrc = mn + (size_t)wave * LL + lane * 4;
  const u16*   ap   = y1 + (size_t)n * CH * LL + (size_t)l15 * LL + g4 * 8;

  f32x4 acc[4][4];
#pragma unroll
  for (int f = 0; f < 4; ++f)
#pragma unroll
    for (int h = 0; h < 4; ++h)
#pragma unroll
      for (int r = 0; r < 4; ++r) acc[f][h][r] = 0.f;

  s16x8 aP[4], aQ[4];

  ALOAD(aP, 0)
  __builtin_amdgcn_sched_barrier(0);
  GLOAD(0, 0) GLOAD(1, 1) GLOAD(2, 2)
  __builtin_amdgcn_sched_barrier(0);
  asm volatile("s_waitcnt vmcnt(16)" ::: "memory");
  __builtin_amdgcn_s_barrier();
  __builtin_amdgcn_sched_barrier(0);

  K1_STEP(0, aP, aQ, 3, 0, "20", 1, 1, 1)
#pragma unroll 1
  for (int kb = 1; kb <= 57; kb += 4) {
    K1_STEP(kb,     aQ, aP, 0, 1, "20", 1, 1, 1)
    K1_STEP(kb + 1, aP, aQ, 1, 2, "20", 1, 1, 1)
    K1_STEP(kb + 2, aQ, aP, 2, 3, "20", 1, 1, 1)
    K1_STEP(kb + 3, aP, aQ, 3, 0, "20", 1, 1, 1)
  }
  K1_STEP(61, aQ, aP, 0, 1, "12", 1, 0, 1)
  K1_STEP(62, aP, aQ, 0, 2, "4",  1, 0, 1)
  K1_STEP(63, aQ, aP, 0, 3, "0",  0, 0, 0)

  // ---- epilogue: y2 (acc) -> yT col-major bf16, overlaid on smem ----
  __syncthreads();                     // all waves done reading stage buffers
  u16* yT = (u16*)&smem[0][0];         // yT[c*72 + r], 256 x 72 u16 = 36 KiB
#pragma unroll
  for (int f = 0; f < 4; ++f)
#pragma unroll
    for (int h = 0; h < 4; ++h) {
      const int c = wave * 64 + h * 16 + l15;
      *(s16x4*)(&yT[c * 72 + f * 16 + g4 * 4]) = pack4c(acc[f][h]);
    }
  __syncthreads();

  // ---- projection: out = Wb(128x192) * [xb;y1;y2] + b ----
  f32x4 acc2[8][4];
#pragma unroll
  for (int f = 0; f < 8; ++f)
#pragma unroll
    for (int h = 0; h < 4; ++h)
#pragma unroll
      for (int r = 0; r < 4; ++r) acc2[f][h][r] = 0.f;

  const size_t cb = (size_t)n * CH * LL + colb + l15;
  const u16* xp  = xb + cb + (size_t)(g4 * 8) * LL;
  const u16* y1p = y1 + cb + (size_t)(g4 * 8) * LL;
  const u16* wq  = Wb + (size_t)l15 * 192 + g4 * 8;

#pragma unroll
  for (int kc = 0; kc < 6; ++kc) {
    const int k0 = kc * 32;
    s16x8 b[4];
    if (kc < 4) {
      const u16* src = (kc < 2) ? (xp + (size_t)k0 * LL)
                                : (y1p + (size_t)(k0 - 64) * LL);
#pragma unroll
      for (int h = 0; h < 4; ++h)
#pragma unroll
        for (int j = 0; j < 8; ++j)
          b[h][j] = (short)src[(size_t)j * LL + h * 16];
    } else {
      const int rb = (kc - 4) * 32 + g4 * 8;
#pragma unroll
      for (int h = 0; h < 4; ++h)
        b[h] = *(const s16x8*)(&yT[(wave * 64 + h * 16 + l15) * 72 + rb]);
    }
#pragma unroll
    for (int f = 0; f < 8; ++f) {
      s16x8 af = *(const s16x8*)(wq + (size_t)(f * 16) * 192 + k0);
#pragma unroll
      for (int h = 0; h < 4; ++h)
        acc2[f][h] = __builtin_amdgcn_mfma_f32_16x16x32_bf16(af, b[h], acc2[f][h], 0, 0, 0);
    }
  }

  float* op = out + (size_t)n * OUTC * LL + colb + l15;
#pragma unroll
  for (int f = 0; f < 8; ++f)
#pragma unroll
    for (int h = 0; h < 4; ++h)
#pragma unroll
      for (int r = 0; r < 4; ++r) {
        const int row = f * 16 + g4 * 4 + r;
        op[(size_t)row * LL + h * 16] = acc2[f][h][r] + bias[row];
      }
}

extern "C" void kernel_launch(void* const* d_in, const int* in_sizes, int n_in,
                              void* d_out, int out_size, void* d_ws, size_t ws_size,
                              hipStream_t stream)
{
  const float* x = (const float*)d_in[0];
  const float* m = (const float*)d_in[1];
  const float* W = (const float*)d_in[2];
  const float* b = (const float*)d_in[3];
  float* out = (float*)d_out;

  // workspace layout (u16 elems): y1 | xb | Wb
  u16* y1 = (u16*)d_ws;                          //  8 MiB
  u16* xb = y1 + (size_t)NB * CH * LL;           //  8 MiB
  u16* Wb = xb + (size_t)NB * CH * LL;           // 48 KiB

  cvt_inputs<<<dim3(2060), dim3(256), 0, stream>>>(x, W, xb, Wb);
  prop1<<<dim3(NB * 8), dim3(256), 0, stream>>>(xb, m, y1);
  prop2m_proj<<<dim3(NB * 8), dim3(256), 0, stream>>>(y1, m, xb, Wb, b, out);
}